// Round 2
// baseline (1249.684 us; speedup 1.0000x reference)
//
#include <hip/hip_runtime.h>
#include <hip/hip_bf16.h>

#define NROWS 6272
#define MROWS 32768
#define DDIM  384
#define NB    8
#define PPB   784
#define BN    128
#define BMT   128
#define BK    32
#define MSPLIT 8
#define MC    (MROWS / MSPLIT)     // 4096
#define MTILES (MC / BMT)          // 32
#define KSTEPS (DDIM / BK)         // 12
#define LDSW  40                   // 32 + 8 pad (bf16 elems) -> 80B row stride
#define CANDW 256                  // 8 chunks * 2 wm * 16 slots
#define KNN   9
#define MARGIN 3.0f

typedef float f32x4 __attribute__((ext_vector_type(4)));
typedef short bf16x8 __attribute__((ext_vector_type(8)));

__device__ __forceinline__ unsigned short f2bf(float f) {
  union { float f; unsigned int u; } c; c.f = f;
  unsigned int u = c.u + 0x7FFFu + ((c.u >> 16) & 1u);  // RNE
  return (unsigned short)(u >> 16);
}
__device__ __forceinline__ unsigned int pk2(float a, float b) {
  return (unsigned int)f2bf(a) | ((unsigned int)f2bf(b) << 16);
}
__device__ __forceinline__ float wredsum(float v) {
#pragma unroll
  for (int m = 32; m; m >>= 1) v += __shfl_xor(v, m, 64);
  return v;
}

// ---------------------------------------------------------------- ynorm
__global__ __launch_bounds__(256) void ynorm_kernel(
    const float* __restrict__ bank, float* __restrict__ ynorm) {
  const int wave = threadIdx.x >> 6, lane = threadIdx.x & 63;
  const int m = blockIdx.x * 4 + wave;
  const float* y = bank + (size_t)m * DDIM;
  float s = 0.f;
#pragma unroll
  for (int j = 0; j < 6; ++j) { float v = y[lane + 64 * j]; s = fmaf(v, v, s); }
  s = wredsum(s);
  if (lane == 0) ynorm[m] = s;
}

// ------------------------------------------------- hot: bf16 MFMA min-candidates
// grid (NROWS/BN)*MSPLIT; blockIdx%8 = M-chunk (maps 1:1 onto XCDs).
__global__ __launch_bounds__(256, 2) void dist_min_kernel(
    const float* __restrict__ emb, const float* __restrict__ bank,
    const float* __restrict__ ynorm, unsigned int* __restrict__ cand) {
  __shared__ unsigned short Al[BN * LDSW];
  __shared__ unsigned short Bl[BMT * LDSW];

  const int bid = blockIdx.x;
  const int ms = bid & (MSPLIT - 1);
  const int bn = bid >> 3;
  const int t = threadIdx.x;
  const int lane = t & 63;
  const int wave = t >> 6;
  const int wn = wave >> 1, wm = wave & 1;
  const int l15 = lane & 15, l4 = lane >> 4;

  const int srow = t >> 1;          // 0..127
  const int scol = (t & 1) * 16;    // 0 or 16
  const float* Asrc = emb + (size_t)(bn * BN + srow) * DDIM + scol;
  const float* Bbase = bank + (size_t)ms * MC * DDIM;

  float rmv[4][4];
  unsigned int rmi[4][4];
#pragma unroll
  for (int a = 0; a < 4; ++a)
#pragma unroll
    for (int b = 0; b < 4; ++b) { rmv[a][b] = 3.4e38f; rmi[a][b] = 0u; }

  for (int mt = 0; mt < MTILES; ++mt) {
    f32x4 acc[4][4];
#pragma unroll
    for (int nf = 0; nf < 4; ++nf)
#pragma unroll
      for (int mf = 0; mf < 4; ++mf) {
        acc[nf][mf][0] = 0.f; acc[nf][mf][1] = 0.f;
        acc[nf][mf][2] = 0.f; acc[nf][mf][3] = 0.f;
      }
    const float* Bsrc = Bbase + (size_t)(mt * BMT + srow) * DDIM + scol;

    for (int ks = 0; ks < KSTEPS; ++ks) {
      const int k0 = ks * BK;
      float4 a0 = *(const float4*)(Asrc + k0);
      float4 a1 = *(const float4*)(Asrc + k0 + 4);
      float4 a2 = *(const float4*)(Asrc + k0 + 8);
      float4 a3 = *(const float4*)(Asrc + k0 + 12);
      float4 b0 = *(const float4*)(Bsrc + k0);
      float4 b1 = *(const float4*)(Bsrc + k0 + 4);
      float4 b2 = *(const float4*)(Bsrc + k0 + 8);
      float4 b3 = *(const float4*)(Bsrc + k0 + 12);
      uint4 alo = { pk2(a0.x,a0.y), pk2(a0.z,a0.w), pk2(a1.x,a1.y), pk2(a1.z,a1.w) };
      uint4 ahi = { pk2(a2.x,a2.y), pk2(a2.z,a2.w), pk2(a3.x,a3.y), pk2(a3.z,a3.w) };
      uint4 blo = { pk2(b0.x,b0.y), pk2(b0.z,b0.w), pk2(b1.x,b1.y), pk2(b1.z,b1.w) };
      uint4 bhi = { pk2(b2.x,b2.y), pk2(b2.z,b2.w), pk2(b3.x,b3.y), pk2(b3.z,b3.w) };
      *(uint4*)&Al[srow * LDSW + scol]     = alo;
      *(uint4*)&Al[srow * LDSW + scol + 8] = ahi;
      *(uint4*)&Bl[srow * LDSW + scol]     = blo;
      *(uint4*)&Bl[srow * LDSW + scol + 8] = bhi;
      __syncthreads();

      bf16x8 af[4], bfr[4];
#pragma unroll
      for (int nf = 0; nf < 4; ++nf)
        af[nf] = *(const bf16x8*)&Al[(wn * 64 + nf * 16 + l15) * LDSW + l4 * 8];
#pragma unroll
      for (int mf = 0; mf < 4; ++mf)
        bfr[mf] = *(const bf16x8*)&Bl[(wm * 64 + mf * 16 + l15) * LDSW + l4 * 8];
#pragma unroll
      for (int nf = 0; nf < 4; ++nf)
#pragma unroll
        for (int mf = 0; mf < 4; ++mf)
          acc[nf][mf] = __builtin_amdgcn_mfma_f32_16x16x32_bf16(
              af[nf], bfr[mf], acc[nf][mf], 0, 0, 0);
      __syncthreads();
    }

    // fold: s = ynorm[m] - 2*dot ; per-lane running min over its column slot
    const int mcol0 = ms * MC + mt * BMT + wm * 64 + l15;
#pragma unroll
    for (int mf = 0; mf < 4; ++mf) {
      const float yv = ynorm[mcol0 + mf * 16];
      const unsigned int midx = (unsigned int)(mcol0 + mf * 16);
#pragma unroll
      for (int nf = 0; nf < 4; ++nf)
#pragma unroll
        for (int r = 0; r < 4; ++r) {
          float v = fmaf(-2.f, acc[nf][mf][r], yv);
          if (v < rmv[nf][r]) { rmv[nf][r] = v; rmi[nf][r] = midx; }
        }
    }
  }

  // chunk-min butterfly within 16-lane group; emit slots within MARGIN
#pragma unroll
  for (int nf = 0; nf < 4; ++nf)
#pragma unroll
    for (int r = 0; r < 4; ++r) {
      float cm = rmv[nf][r];
      cm = fminf(cm, __shfl_xor(cm, 1, 64));
      cm = fminf(cm, __shfl_xor(cm, 2, 64));
      cm = fminf(cm, __shfl_xor(cm, 4, 64));
      cm = fminf(cm, __shfl_xor(cm, 8, 64));
      const int n = bn * BN + wn * 64 + nf * 16 + l4 * 4 + r;
      unsigned int o = (rmv[nf][r] <= cm + MARGIN) ? rmi[nf][r] : 0xFFFFFFFFu;
      cand[(size_t)n * CANDW + ms * 32 + wm * 16 + l15] = o;
    }
}

// ------------------------------------------------- exact fp32 rescore (1 wave/row)
__global__ __launch_bounds__(64) void rescore_kernel(
    const float* __restrict__ emb, const float* __restrict__ bank,
    const float* __restrict__ ynorm, const unsigned int* __restrict__ cand,
    float* __restrict__ outmap, float* __restrict__ ps, int* __restrict__ loc) {
  const int n = blockIdx.x;
  const int lane = threadIdx.x;
  const float* x = emb + (size_t)n * DDIM;
  float xv[6];
#pragma unroll
  for (int j = 0; j < 6; ++j) xv[j] = x[lane + 64 * j];
  float xn = 0.f;
#pragma unroll
  for (int j = 0; j < 6; ++j) xn = fmaf(xv[j], xv[j], xn);
  xn = wredsum(xn);

  float best = 3.4e38f; int bidx = 0x7FFFFFFF;
  for (int q = 0; q < 4; ++q) {
    const unsigned int cq = cand[(size_t)n * CANDW + q * 64 + lane];
    for (int s = 0; s < 64; ++s) {
      const unsigned int m = __shfl(cq, s, 64);
      if (m == 0xFFFFFFFFu) continue;
      const float* y = bank + (size_t)m * DDIM;
      float d = 0.f;
#pragma unroll
      for (int j = 0; j < 6; ++j) d = fmaf(xv[j], y[lane + 64 * j], d);
      d = wredsum(d);
      const float v = fmaf(-2.f, d, xn + ynorm[m]);
      if (v < best || (v == best && (int)m < bidx)) { best = v; bidx = (int)m; }
    }
  }
  if (lane == 0) {
    const float sc = sqrtf(fmaxf(best, 0.f));
    outmap[n] = sc; ps[n] = sc; loc[n] = bidx;
  }
}

// ------------------------------------------------- per-batch argmax (first-index ties)
__global__ __launch_bounds__(256) void argmax_kernel(
    const float* __restrict__ ps, const int* __restrict__ loc,
    float* __restrict__ score, int* __restrict__ maxrow, int* __restrict__ nnidx) {
  __shared__ float sv[256]; __shared__ int si[256];
  const int b = blockIdx.x, t = threadIdx.x;
  float best = -3.4e38f; int bi = 0x7FFFFFFF;
  for (int p = t; p < PPB; p += 256) {
    const float v = ps[b * PPB + p];
    if (v > best || (v == best && p < bi)) { best = v; bi = p; }
  }
  sv[t] = best; si[t] = bi;
  __syncthreads();
  for (int s = 128; s > 0; s >>= 1) {
    if (t < s) {
      if (sv[t + s] > sv[t] || (sv[t + s] == sv[t] && si[t + s] < si[t])) {
        sv[t] = sv[t + s]; si[t] = si[t + s];
      }
    }
    __syncthreads();
  }
  if (t == 0) {
    score[b] = sv[0];
    maxrow[b] = b * PPB + si[0];
    nnidx[b] = loc[b * PPB + si[0]];
  }
}

// ------------------------------------------------- d2: nn_sample vs bank (squared)
__global__ __launch_bounds__(256) void d2_kernel(
    const float* __restrict__ bank, const float* __restrict__ ynorm,
    const int* __restrict__ nnidx, float* __restrict__ d2) {
  __shared__ float nnf[NB][DDIM];
  __shared__ float nno[NB];
  const int t = threadIdx.x;
  for (int b = 0; b < NB; ++b) {
    const int m = nnidx[b];
    for (int j = t; j < DDIM; j += 256) nnf[b][j] = bank[(size_t)m * DDIM + j];
  }
  if (t < NB) nno[t] = ynorm[nnidx[t]];
  __syncthreads();
  const int wave = t >> 6, lane = t & 63;
  const int m = blockIdx.x * 4 + wave;
  const float* y = bank + (size_t)m * DDIM;
  float yv[6];
#pragma unroll
  for (int j = 0; j < 6; ++j) yv[j] = y[lane + 64 * j];
  const float yn = ynorm[m];
  for (int b = 0; b < NB; ++b) {
    float d = 0.f;
#pragma unroll
    for (int j = 0; j < 6; ++j) d = fmaf(yv[j], nnf[b][lane + 64 * j], d);
    d = wredsum(d);
    if (lane == 0) d2[(size_t)b * MROWS + m] = fmaxf(fmaf(-2.f, d, nno[b] + yn), 0.f);
  }
}

// ------------------------------------------------- iterative top-9 (ascending)
__global__ __launch_bounds__(256) void topk_kernel(
    const float* __restrict__ d2, int* __restrict__ support) {
  __shared__ float sv[256]; __shared__ int si[256];
  __shared__ int picked[KNN];
  const int b = blockIdx.x, t = threadIdx.x;
  const float* row = d2 + (size_t)b * MROWS;
  for (int k = 0; k < KNN; ++k) {
    float best = 3.4e38f; int bi = 0x7FFFFFFF;
    for (int m = t; m < MROWS; m += 256) {
      const float v = row[m];
      bool skip = false;
      for (int j = 0; j < k; ++j) skip = skip || (picked[j] == m);
      if (!skip && (v < best || (v == best && m < bi))) { best = v; bi = m; }
    }
    sv[t] = best; si[t] = bi;
    __syncthreads();
    for (int s = 128; s > 0; s >>= 1) {
      if (t < s) {
        if (sv[t + s] < sv[t] || (sv[t + s] == sv[t] && si[t + s] < si[t])) {
          sv[t] = sv[t + s]; si[t] = si[t + s];
        }
      }
      __syncthreads();
    }
    if (t == 0) { picked[k] = si[0]; support[b * KNN + k] = si[0]; }
    __syncthreads();
  }
}

// ------------------------------------------------- d3 + softmax + pred_score
__global__ __launch_bounds__(256) void final_kernel(
    const float* __restrict__ emb, const float* __restrict__ bank,
    const float* __restrict__ ynorm, const int* __restrict__ support,
    const int* __restrict__ maxrow, const float* __restrict__ score,
    float* __restrict__ pred) {
  __shared__ float d3s[NB][KNN];
  const int t = threadIdx.x, wave = t >> 6, lane = t & 63;
  for (int b = wave; b < NB; b += 4) {
    const float* x = emb + (size_t)maxrow[b] * DDIM;
    float xv[6];
#pragma unroll
    for (int j = 0; j < 6; ++j) xv[j] = x[lane + 64 * j];
    float xn = 0.f;
#pragma unroll
    for (int j = 0; j < 6; ++j) xn = fmaf(xv[j], xv[j], xn);
    xn = wredsum(xn);
    for (int k = 0; k < KNN; ++k) {
      const int m = support[b * KNN + k];
      const float* y = bank + (size_t)m * DDIM;
      float d = 0.f;
#pragma unroll
      for (int j = 0; j < 6; ++j) d = fmaf(xv[j], y[lane + 64 * j], d);
      d = wredsum(d);
      if (lane == 0) d3s[b][k] = sqrtf(fmaxf(fmaf(-2.f, d, xn + ynorm[m]), 0.f));
    }
  }
  __syncthreads();
  if (t < NB) {
    float mx = -3.4e38f;
    for (int k = 0; k < KNN; ++k) mx = fmaxf(mx, d3s[t][k]);
    float sum = 0.f, e0 = 0.f;
    for (int k = 0; k < KNN; ++k) {
      const float e = expf(d3s[t][k] - mx);
      if (k == 0) e0 = e;
      sum += e;
    }
    pred[t] = (1.f - e0 / sum) * score[t];
  }
}

extern "C" void kernel_launch(void* const* d_in, const int* in_sizes, int n_in,
                              void* d_out, int out_size, void* d_ws, size_t ws_size,
                              hipStream_t stream) {
  (void)in_sizes; (void)n_in; (void)out_size; (void)ws_size;
  const float* emb = (const float*)d_in[0];
  const float* bank = (const float*)d_in[1];
  float* out = (float*)d_out;

  char* ws = (char*)d_ws;
  size_t o = 0;
  float* ynorm = (float*)(ws + o);        o += (size_t)MROWS * 4;          // 128 KB
  unsigned int* cand = (unsigned int*)(ws + o); o += (size_t)NROWS * CANDW * 4; // 6.1 MB
  float* ps = (float*)(ws + o);           o += (size_t)NROWS * 4;
  int* loc = (int*)(ws + o);              o += (size_t)NROWS * 4;
  float* d2 = (float*)(ws + o);           o += (size_t)NB * MROWS * 4;     // 1 MB
  float* score = (float*)(ws + o);        o += 256;
  int* maxrow = (int*)(ws + o);           o += 256;
  int* nnidx = (int*)(ws + o);            o += 256;
  int* support = (int*)(ws + o);          o += 512;

  ynorm_kernel<<<MROWS / 4, 256, 0, stream>>>(bank, ynorm);
  dist_min_kernel<<<(NROWS / BN) * MSPLIT, 256, 0, stream>>>(emb, bank, ynorm, cand);
  rescore_kernel<<<NROWS, 64, 0, stream>>>(emb, bank, ynorm, cand, out, ps, loc);
  argmax_kernel<<<NB, 256, 0, stream>>>(ps, loc, score, maxrow, nnidx);
  d2_kernel<<<MROWS / 4, 256, 0, stream>>>(bank, ynorm, nnidx, d2);
  topk_kernel<<<NB, 256, 0, stream>>>(d2, support);
  final_kernel<<<1, 256, 0, stream>>>(emb, bank, ynorm, support, maxrow, score, out + NROWS);
}

// Round 4
// 532.273 us; speedup vs baseline: 2.3478x; 2.3478x over previous
//
#include <hip/hip_runtime.h>
#include <hip/hip_bf16.h>

#define NROWS 6272
#define MROWS 32768
#define DDIM  384
#define NB    8
#define PPB   784
#define BN    128
#define BMT   128
#define MSPLIT 16
#define MC    (MROWS / MSPLIT)     // 2048
#define MTILES (MC / BMT)          // 16
#define KSTEPS (DDIM / 32)         // 12
#define CANDW (MSPLIT * 32)        // 512
#define KNN   9
#define TSEG  16
#define MARGIN 3.0f

typedef float f32x4 __attribute__((ext_vector_type(4)));
typedef short bf16x8 __attribute__((ext_vector_type(8)));

__device__ __forceinline__ unsigned short f2bf(float f) {
  union { float f; unsigned int u; } c; c.f = f;
  unsigned int u = c.u + 0x7FFFu + ((c.u >> 16) & 1u);  // RNE
  return (unsigned short)(u >> 16);
}
__device__ __forceinline__ unsigned int pk2(float a, float b) {
  return (unsigned int)f2bf(a) | ((unsigned int)f2bf(b) << 16);
}
__device__ __forceinline__ float wredsum(float v) {
#pragma unroll
  for (int m = 32; m; m >>= 1) v += __shfl_xor(v, m, 64);
  return v;
}
__device__ __forceinline__ void glds16(const void* g, void* l) {
  __builtin_amdgcn_global_load_lds(
      (const __attribute__((address_space(1))) unsigned int*)g,
      (__attribute__((address_space(3))) unsigned int*)l, 16, 0, 0);
}

// ---------------------------------------------------------------- fp32 -> bf16 copy
__global__ __launch_bounds__(256) void cvt_bf16_kernel(
    const float* __restrict__ src, unsigned short* __restrict__ dst) {
  const int i = blockIdx.x * 256 + threadIdx.x;  // 8 elems per thread
  const float4 a = ((const float4*)src)[i * 2];
  const float4 b = ((const float4*)src)[i * 2 + 1];
  uint4 o = { pk2(a.x, a.y), pk2(a.z, a.w), pk2(b.x, b.y), pk2(b.z, b.w) };
  ((uint4*)dst)[i] = o;
}

// ---------------------------------------------------------------- ynorm (exact fp32)
__global__ __launch_bounds__(256) void ynorm_kernel(
    const float* __restrict__ bank, float* __restrict__ ynorm) {
  const int wave = threadIdx.x >> 6, lane = threadIdx.x & 63;
  const int m = blockIdx.x * 4 + wave;
  const float* y = bank + (size_t)m * DDIM;
  float s = 0.f;
#pragma unroll
  for (int j = 0; j < 6; ++j) { float v = y[lane + 64 * j]; s = fmaf(v, v, s); }
  s = wredsum(s);
  if (lane == 0) ynorm[m] = s;
}

// ------------------------------------------------- hot: bf16 MFMA min-candidates
// grid (NROWS/BN)*MSPLIT = 784; ms = bid&15 -> chunk c on XCD c%8 (L2-resident B).
__global__ __launch_bounds__(256) void dist_min_kernel(
    const unsigned short* __restrict__ embbf, const unsigned short* __restrict__ bankbf,
    const float* __restrict__ ynorm, unsigned int* __restrict__ cand) {
  __shared__ unsigned short Al[BN * 32];    // linear [128][32] bf16, 64B rows
  __shared__ unsigned short Bl[BMT * 32];
  __shared__ float ynLds[MC];

  const int bid = blockIdx.x;
  const int ms = bid & (MSPLIT - 1);
  const int bn = bid >> 4;
  const int t = threadIdx.x;
  const int lane = t & 63;
  const int wave = t >> 6;
  const int wn = wave >> 1, wm = wave & 1;
  const int l15 = lane & 15, l4 = lane >> 4;

  // ynorm chunk slice -> LDS
  for (int i = t; i < MC; i += 256) ynLds[i] = ynorm[ms * MC + i];

  // staging source pointers (global_load_lds: lds dest = uniform base + lane*16)
  const int seg0 = wave * 2, seg1 = wave * 2 + 1;
  const int sRow = lane >> 2;
  const int sColB = (lane & 3) * 16;  // bytes
  const char* aG0 = (const char*)embbf + ((size_t)(bn * BN + seg0 * 16 + sRow)) * 768 + sColB;
  const char* aG1 = (const char*)embbf + ((size_t)(bn * BN + seg1 * 16 + sRow)) * 768 + sColB;
  const char* bGb = (const char*)bankbf + ((size_t)(ms * MC + sRow)) * 768 + sColB;
  unsigned short* aL0 = &Al[seg0 * 512];
  unsigned short* aL1 = &Al[seg1 * 512];
  unsigned short* bL0 = &Bl[seg0 * 512];
  unsigned short* bL1 = &Bl[seg1 * 512];

  int rmk[4][4];
#pragma unroll
  for (int a = 0; a < 4; ++a)
#pragma unroll
    for (int b = 0; b < 4; ++b) rmk[a][b] = 0x7F800000;  // +inf

  for (int mt = 0; mt < MTILES; ++mt) {
    f32x4 acc[4][4];
#pragma unroll
    for (int nf = 0; nf < 4; ++nf)
#pragma unroll
      for (int mf = 0; mf < 4; ++mf) {
        acc[nf][mf][0] = 0.f; acc[nf][mf][1] = 0.f;
        acc[nf][mf][2] = 0.f; acc[nf][mf][3] = 0.f;
      }
    // FIX(R3->R4): include the per-wave segment row offset (seg*16) in the
    // B-tile global source. R3 staged rows 0..31 of each tile replicated 4x.
    const char* bG0 = bGb + ((size_t)mt * BMT + seg0 * 16) * 768;
    const char* bG1 = bGb + ((size_t)mt * BMT + seg1 * 16) * 768;

    for (int ks = 0; ks < KSTEPS; ++ks) {
      const int kb = ks * 64;
      glds16(aG0 + kb, aL0);
      glds16(aG1 + kb, aL1);
      glds16(bG0 + kb, bL0);
      glds16(bG1 + kb, bL1);
      __syncthreads();   // drains vmcnt (compiler) -> LDS tiles ready

      bf16x8 af[4], bfr[4];
#pragma unroll
      for (int nf = 0; nf < 4; ++nf)
        af[nf] = *(const bf16x8*)&Al[(wn * 64 + nf * 16 + l15) * 32 + l4 * 8];
#pragma unroll
      for (int mf = 0; mf < 4; ++mf)
        bfr[mf] = *(const bf16x8*)&Bl[(wm * 64 + mf * 16 + l15) * 32 + l4 * 8];
#pragma unroll
      for (int nf = 0; nf < 4; ++nf)
#pragma unroll
        for (int mf = 0; mf < 4; ++mf)
          acc[nf][mf] = __builtin_amdgcn_mfma_f32_16x16x32_bf16(
              af[nf], bfr[mf], acc[nf][mf], 0, 0, 0);
      __syncthreads();   // reads done before next ks overwrites
    }

    // fold: key = trunc(max(ynorm-2dot,0)) | (mt,mf) code ; signed-int min
    float yv4[4];
#pragma unroll
    for (int mf = 0; mf < 4; ++mf) yv4[mf] = ynLds[mt * BMT + wm * 64 + mf * 16 + l15];
#pragma unroll
    for (int mf = 0; mf < 4; ++mf) {
      const unsigned int code = (unsigned int)((mt * 4 + mf) << 5);
#pragma unroll
      for (int nf = 0; nf < 4; ++nf)
#pragma unroll
        for (int r = 0; r < 4; ++r) {
          float v = fmaf(-2.f, acc[nf][mf][r], yv4[mf]);
          v = fmaxf(v, 0.f);
          const int key = (int)((__float_as_uint(v) & 0xFFFFF800u) | code);
          rmk[nf][r] = min(rmk[nf][r], key);
        }
    }
  }

  // emit candidates within MARGIN of the 32-slot group min
#pragma unroll
  for (int nf = 0; nf < 4; ++nf)
#pragma unroll
    for (int r = 0; r < 4; ++r) {
      int k = rmk[nf][r];
      int cm = k;
      cm = min(cm, __shfl_xor(cm, 1, 64));
      cm = min(cm, __shfl_xor(cm, 2, 64));
      cm = min(cm, __shfl_xor(cm, 4, 64));
      cm = min(cm, __shfl_xor(cm, 8, 64));
      const float vf = __uint_as_float((unsigned int)k & 0xFFFFF800u);
      const float cf = __uint_as_float((unsigned int)cm & 0xFFFFF800u);
      unsigned int out = 0xFFFFFFFFu;
      if (vf <= cf + MARGIN) {
        const unsigned int code = ((unsigned int)k >> 5) & 63u;
        out = (unsigned int)(ms * MC + (code >> 2) * BMT + wm * 64 + (code & 3) * 16 + l15);
      }
      const int n = bn * BN + wn * 64 + nf * 16 + l4 * 4 + r;
      cand[(size_t)n * CANDW + ms * 32 + wm * 16 + l15] = out;
    }
}

// ------------------------------------------------- exact fp32 rescore (4 waves/row)
__global__ __launch_bounds__(256) void rescore_kernel(
    const float* __restrict__ emb, const float* __restrict__ bank,
    const float* __restrict__ ynorm, const unsigned int* __restrict__ cand,
    float* __restrict__ outmap, float* __restrict__ ps, int* __restrict__ loc) {
  __shared__ float sbv[4]; __shared__ int sbi[4];
  const int n = blockIdx.x;
  const int t = threadIdx.x, wave = t >> 6, lane = t & 63;
  const float* x = emb + (size_t)n * DDIM;
  float xv[6];
#pragma unroll
  for (int j = 0; j < 6; ++j) xv[j] = x[lane + 64 * j];
  float xn = 0.f;
#pragma unroll
  for (int j = 0; j < 6; ++j) xn = fmaf(xv[j], xv[j], xn);
  xn = wredsum(xn);

  float best = 3.4e38f; int bidx = 0x7FFFFFFF;
  for (int q = wave * 2; q < wave * 2 + 2; ++q) {
    const unsigned int cq = cand[(size_t)n * CANDW + q * 64 + lane];
    for (int s = 0; s < 64; ++s) {
      const unsigned int m = __shfl(cq, s, 64);
      if (m == 0xFFFFFFFFu) continue;
      const float* y = bank + (size_t)m * DDIM;
      float d = 0.f;
#pragma unroll
      for (int j = 0; j < 6; ++j) d = fmaf(xv[j], y[lane + 64 * j], d);
      d = wredsum(d);
      const float v = fmaf(-2.f, d, xn + ynorm[m]);
      if (v < best || (v == best && (int)m < bidx)) { best = v; bidx = (int)m; }
    }
  }
  if (lane == 0) { sbv[wave] = best; sbi[wave] = bidx; }
  __syncthreads();
  if (t == 0) {
    float bv = sbv[0]; int bi = sbi[0];
#pragma unroll
    for (int w = 1; w < 4; ++w)
      if (sbv[w] < bv || (sbv[w] == bv && sbi[w] < bi)) { bv = sbv[w]; bi = sbi[w]; }
    const float sc = sqrtf(fmaxf(bv, 0.f));
    outmap[n] = sc; ps[n] = sc; loc[n] = bi;
  }
}

// ------------------------------------------------- per-batch argmax (first-index ties)
__global__ __launch_bounds__(256) void argmax_kernel(
    const float* __restrict__ ps, const int* __restrict__ loc,
    float* __restrict__ score, int* __restrict__ maxrow, int* __restrict__ nnidx) {
  __shared__ float sv[256]; __shared__ int si[256];
  const int b = blockIdx.x, t = threadIdx.x;
  float best = -3.4e38f; int bi = 0x7FFFFFFF;
  for (int p = t; p < PPB; p += 256) {
    const float v = ps[b * PPB + p];
    if (v > best || (v == best && p < bi)) { best = v; bi = p; }
  }
  sv[t] = best; si[t] = bi;
  __syncthreads();
  for (int s = 128; s > 0; s >>= 1) {
    if (t < s) {
      if (sv[t + s] > sv[t] || (sv[t + s] == sv[t] && si[t + s] < si[t])) {
        sv[t] = sv[t + s]; si[t] = si[t + s];
      }
    }
    __syncthreads();
  }
  if (t == 0) {
    score[b] = sv[0];
    maxrow[b] = b * PPB + si[0];
    nnidx[b] = loc[b * PPB + si[0]];
  }
}

// ------------------------------------------------- d2: nn_sample vs bank (squared)
__global__ __launch_bounds__(256) void d2_kernel(
    const float* __restrict__ bank, const float* __restrict__ ynorm,
    const int* __restrict__ nnidx, float* __restrict__ d2) {
  __shared__ float nnf[NB][DDIM];
  __shared__ float nno[NB];
  const int t = threadIdx.x;
  for (int b = 0; b < NB; ++b) {
    const int m = nnidx[b];
    for (int j = t; j < DDIM; j += 256) nnf[b][j] = bank[(size_t)m * DDIM + j];
  }
  if (t < NB) nno[t] = ynorm[nnidx[t]];
  __syncthreads();
  const int wave = t >> 6, lane = t & 63;
  const int m = blockIdx.x * 4 + wave;
  const float* y = bank + (size_t)m * DDIM;
  float yv[6];
#pragma unroll
  for (int j = 0; j < 6; ++j) yv[j] = y[lane + 64 * j];
  const float yn = ynorm[m];
  for (int b = 0; b < NB; ++b) {
    float d = 0.f;
#pragma unroll
    for (int j = 0; j < 6; ++j) d = fmaf(yv[j], nnf[b][lane + 64 * j], d);
    d = wredsum(d);
    if (lane == 0) d2[(size_t)b * MROWS + m] = fmaxf(fmaf(-2.f, d, nno[b] + yn), 0.f);
  }
}

// ------------------------------------------------- top-9 phase 1: per-segment top-9
__global__ __launch_bounds__(256) void topk1_kernel(
    const float* __restrict__ d2, float* __restrict__ pv, int* __restrict__ pi) {
  __shared__ float sv[256]; __shared__ int si[256];
  const int b = blockIdx.x / TSEG, seg = blockIdx.x % TSEG;
  const float* base = d2 + (size_t)b * MROWS + seg * 2048;
  const int t = threadIdx.x, off = t * 8;
  float v[8];
  const float4 x0 = *(const float4*)(base + off);
  const float4 x1 = *(const float4*)(base + off + 4);
  v[0] = x0.x; v[1] = x0.y; v[2] = x0.z; v[3] = x0.w;
  v[4] = x1.x; v[5] = x1.y; v[6] = x1.z; v[7] = x1.w;
  for (int k = 0; k < KNN; ++k) {
    float lb = v[0]; int li = 0;
#pragma unroll
    for (int i = 1; i < 8; ++i)
      if (v[i] < lb) { lb = v[i]; li = i; }
    sv[t] = lb; si[t] = off + li;
    __syncthreads();
    for (int s = 128; s > 0; s >>= 1) {
      if (t < s) {
        if (sv[t + s] < sv[t] || (sv[t + s] == sv[t] && si[t + s] < si[t])) {
          sv[t] = sv[t + s]; si[t] = si[t + s];
        }
      }
      __syncthreads();
    }
    const int widx = si[0];
    if (t == 0) {
      pv[(size_t)(b * TSEG + seg) * KNN + k] = sv[0];
      pi[(size_t)(b * TSEG + seg) * KNN + k] = seg * 2048 + widx;
    }
    __syncthreads();
#pragma unroll
    for (int i = 0; i < 8; ++i)
      if (off + i == widx) v[i] = 3.4e38f;
  }
}

// ------------------------------------------------- top-9 phase 2: merge 144 -> 9
__global__ __launch_bounds__(64) void topk2_kernel(
    const float* __restrict__ pv, const int* __restrict__ pi, int* __restrict__ support) {
  const int b = blockIdx.x, lane = threadIdx.x;
  float v[3]; int ix[3];
#pragma unroll
  for (int j = 0; j < 3; ++j) {
    const int e = lane + j * 64;
    if (e < TSEG * KNN) { v[j] = pv[(size_t)b * TSEG * KNN + e]; ix[j] = pi[(size_t)b * TSEG * KNN + e]; }
    else { v[j] = 3.4e38f; ix[j] = 0x7FFFFFFF; }
  }
  for (int k = 0; k < KNN; ++k) {
    float bv = v[0]; int bi = ix[0];
#pragma unroll
    for (int j = 1; j < 3; ++j)
      if (v[j] < bv || (v[j] == bv && ix[j] < bi)) { bv = v[j]; bi = ix[j]; }
#pragma unroll
    for (int m = 1; m < 64; m <<= 1) {
      const float ov = __shfl_xor(bv, m, 64);
      const int oi = __shfl_xor(bi, m, 64);
      if (ov < bv || (ov == bv && oi < bi)) { bv = ov; bi = oi; }
    }
    if (lane == 0) support[b * KNN + k] = bi;
#pragma unroll
    for (int j = 0; j < 3; ++j)
      if (ix[j] == bi) v[j] = 3.4e38f;
  }
}

// ------------------------------------------------- d3 + softmax + pred_score
__global__ __launch_bounds__(256) void final_kernel(
    const float* __restrict__ emb, const float* __restrict__ bank,
    const float* __restrict__ ynorm, const int* __restrict__ support,
    const int* __restrict__ maxrow, const float* __restrict__ score,
    float* __restrict__ pred) {
  __shared__ float d3s[NB][KNN];
  const int t = threadIdx.x, wave = t >> 6, lane = t & 63;
  for (int b = wave; b < NB; b += 4) {
    const float* x = emb + (size_t)maxrow[b] * DDIM;
    float xv[6];
#pragma unroll
    for (int j = 0; j < 6; ++j) xv[j] = x[lane + 64 * j];
    float xn = 0.f;
#pragma unroll
    for (int j = 0; j < 6; ++j) xn = fmaf(xv[j], xv[j], xn);
    xn = wredsum(xn);
    for (int k = 0; k < KNN; ++k) {
      const int m = support[b * KNN + k];
      const float* y = bank + (size_t)m * DDIM;
      float d = 0.f;
#pragma unroll
      for (int j = 0; j < 6; ++j) d = fmaf(xv[j], y[lane + 64 * j], d);
      d = wredsum(d);
      if (lane == 0) d3s[b][k] = sqrtf(fmaxf(fmaf(-2.f, d, xn + ynorm[m]), 0.f));
    }
  }
  __syncthreads();
  if (t < NB) {
    float mx = -3.4e38f;
    for (int k = 0; k < KNN; ++k) mx = fmaxf(mx, d3s[t][k]);
    float sum = 0.f, e0 = 0.f;
    for (int k = 0; k < KNN; ++k) {
      const float e = expf(d3s[t][k] - mx);
      if (k == 0) e0 = e;
      sum += e;
    }
    pred[t] = (1.f - e0 / sum) * score[t];
  }
}

extern "C" void kernel_launch(void* const* d_in, const int* in_sizes, int n_in,
                              void* d_out, int out_size, void* d_ws, size_t ws_size,
                              hipStream_t stream) {
  (void)in_sizes; (void)n_in; (void)out_size; (void)ws_size;
  const float* emb = (const float*)d_in[0];
  const float* bank = (const float*)d_in[1];
  float* out = (float*)d_out;

  char* ws = (char*)d_ws;
  size_t o = 0;
  auto alloc = [&](size_t bytes) { void* p = ws + o; o = (o + bytes + 255) & ~(size_t)255; return p; };
  float* ynorm = (float*)alloc((size_t)MROWS * 4);
  unsigned short* embbf = (unsigned short*)alloc((size_t)NROWS * DDIM * 2);
  unsigned short* bankbf = (unsigned short*)alloc((size_t)MROWS * DDIM * 2);
  unsigned int* cand = (unsigned int*)alloc((size_t)NROWS * CANDW * 4);
  float* ps = (float*)alloc((size_t)NROWS * 4);
  int* loc = (int*)alloc((size_t)NROWS * 4);
  float* d2 = (float*)alloc((size_t)NB * MROWS * 4);
  float* pv = (float*)alloc((size_t)NB * TSEG * KNN * 4);
  int* pi = (int*)alloc((size_t)NB * TSEG * KNN * 4);
  float* score = (float*)alloc(256);
  int* maxrow = (int*)alloc(256);
  int* nnidx = (int*)alloc(256);
  int* support = (int*)alloc(512);

  cvt_bf16_kernel<<<NROWS * DDIM / 8 / 256, 256, 0, stream>>>(emb, embbf);
  cvt_bf16_kernel<<<MROWS * DDIM / 8 / 256, 256, 0, stream>>>(bank, bankbf);
  ynorm_kernel<<<MROWS / 4, 256, 0, stream>>>(bank, ynorm);
  dist_min_kernel<<<(NROWS / BN) * MSPLIT, 256, 0, stream>>>(embbf, bankbf, ynorm, cand);
  rescore_kernel<<<NROWS, 256, 0, stream>>>(emb, bank, ynorm, cand, out, ps, loc);
  argmax_kernel<<<NB, 256, 0, stream>>>(ps, loc, score, maxrow, nnidx);
  d2_kernel<<<MROWS / 4, 256, 0, stream>>>(bank, ynorm, nnidx, d2);
  topk1_kernel<<<NB * TSEG, 256, 0, stream>>>(d2, pv, pi);
  topk2_kernel<<<NB, 64, 0, stream>>>(pv, pi, support);
  final_kernel<<<1, 256, 0, stream>>>(emb, bank, ynorm, support, maxrow, score, out + NROWS);
}